// Round 4
// baseline (651.737 us; speedup 1.0000x reference)
//
#include <hip/hip_runtime.h>
#include <hip/hip_bf16.h>

// Problem constants
#define NB    1024   // batch
#define SEQ   512    // max seq len
#define DIM   128    // embedding dim (D)
#define HID   128    // hidden (H)
#define NOPS  16     // OPS
#define FEAT  144    // H + OPS
#define BQ    4      // samples per workgroup
#define AST   144    // sample stride (bf16 elems) inside a slab: breaks bank strides
#define XSLAB (BQ * AST)   // 576 elems per (parity, offset) x-slab

typedef __bf16 bf16x8 __attribute__((ext_vector_type(8)));
typedef float  floatx4 __attribute__((ext_vector_type(4)));

__device__ __forceinline__ float fsig(float x)  { return 1.0f / (1.0f + __expf(-x)); }
__device__ __forceinline__ float ftanhf(float x){ return 2.0f / (1.0f + __expf(-2.0f * x)) - 1.0f; }

// One WG = 512 threads (8 waves) owns BQ=4 samples. Wave w owns unit-chunk w
// for all 4 gate types (gates consumed in-register). 4-STEP X-PACKING: one
// M-packed MFMA block per superstep computes x-gates for 4 samples x 4
// timesteps (A row = sample*4 + off), landing x-gate(sample=quad, t+r, uu) in
// lane (quad,lrow) reg r -> per-step x-gate is a register scalar. In-loop
// serial MFMAs are h-part only (16/wave/step); x-block (16) runs once per 4
// steps. One barrier per step; h double-buffered by step parity; x slabs
// double-buffered by superstep parity (stage x(t+5) at step t).
__global__ __launch_bounds__(512, 2)
void lstm_fused(const int* __restrict__ tokens, const int* __restrict__ lengths,
                const float* __restrict__ onehot, const float* __restrict__ emb,
                const float* __restrict__ Wih, const float* __restrict__ Whh,
                const float* __restrict__ bih, const float* __restrict__ bhh,
                const float* __restrict__ h0, const float* __restrict__ c0,
                const float* __restrict__ linW, const float* __restrict__ linb,
                float* __restrict__ out)
{
    __shared__ __align__(16) __bf16 xbuf[2][4][XSLAB]; // [ss parity][off][s*AST+k]
    __shared__ __align__(16) __bf16 hbuf[2][XSLAB];
    __shared__ __align__(16) float  hlbuf[BQ * HID];

    const int tid  = threadIdx.x;
    const int wave = tid >> 6;
    const int lane = tid & 63;
    const int quad = lane >> 4;
    const int lrow = lane & 15;
    const int bid  = blockIdx.x;

    // ---- Weight B-fragments in registers (loaded once). ----
    // B-layout (16x16x32): lane holds B[k=quad*8+j][n=lrow].
    bf16x8 wfx[4][4], wfh[4][4];
#pragma unroll
    for (int gt = 0; gt < 4; ++gt) {
        const int g = gt * 128 + wave * 16 + lrow;
#pragma unroll
        for (int kt = 0; kt < 4; ++kt) {
            const float* sx = Wih + g * DIM + kt * 32 + quad * 8;
            const float* sh = Whh + g * HID + kt * 32 + quad * 8;
            float4 a = *(const float4*)(sx);
            float4 b = *(const float4*)(sx + 4);
            bf16x8 v;
            v[0] = (__bf16)a.x; v[1] = (__bf16)a.y; v[2] = (__bf16)a.z; v[3] = (__bf16)a.w;
            v[4] = (__bf16)b.x; v[5] = (__bf16)b.y; v[6] = (__bf16)b.z; v[7] = (__bf16)b.w;
            wfx[gt][kt] = v;
            a = *(const float4*)(sh);
            b = *(const float4*)(sh + 4);
            v[0] = (__bf16)a.x; v[1] = (__bf16)a.y; v[2] = (__bf16)a.z; v[3] = (__bf16)a.w;
            v[4] = (__bf16)b.x; v[5] = (__bf16)b.y; v[6] = (__bf16)b.z; v[7] = (__bf16)b.w;
            wfh[gt][kt] = v;
        }
    }

    // ---- Per-lane state: sample = quad, unit = uu = wave*16 + lrow ----
    const int uu = wave * 16 + lrow;
    const int bq = bid * BQ + quad;
    int lenq = lengths[bq]; if (lenq < 1) lenq = 1;
    const int tlast = lenq - 1;

    int Lmax = 0;
#pragma unroll
    for (int s2 = 0; s2 < BQ; ++s2) {
        int l2 = lengths[bid * BQ + s2]; if (l2 < 1) l2 = 1;
        Lmax = (l2 > Lmax) ? l2 : Lmax;
    }

    float bini[4];
#pragma unroll
    for (int gt = 0; gt < 4; ++gt)
        bini[gt] = bih[gt * 128 + uu] + bhh[gt * 128 + uu];

    float c  = c0[uu];
    float hl = 0.0f;

    // ---- Staging thread layout: m = tid>>7 (sample), u = tid&127 (unit) ----
    const int m  = tid >> 7;
    const int u  = tid & 127;
    const int bm = bid * BQ + m;
    const int sm = m * AST + u;

    // zero-fill x slabs so past-length rows stay finite (NaN containment)
    {
        __bf16* xf = &xbuf[0][0][0];
        for (int i = tid; i < 2 * 4 * XSLAB; i += 512) xf[i] = (__bf16)0.0f;
    }
    __syncthreads();

    hbuf[0][sm] = (__bf16)h0[u];
#pragma unroll
    for (int k = 0; k <= 4; ++k) {   // stage x(0..4): always valid (k < SEQ)
        float ek = emb[(size_t)tokens[bm * SEQ + k] * DIM + u];
        xbuf[(k >> 2) & 1][k & 3][sm] = (__bf16)fmaxf(ek, 0.0f);
    }
    float e = emb[(size_t)tokens[bm * SEQ + 5] * DIM + u];   // for t'=5

    // x-frag pointers: A row m=lrow -> (sample = lrow>>2, off = lrow&3)
    const __bf16* xfp[2];
    xfp[0] = &xbuf[0][lrow & 3][(lrow >> 2) * AST + quad * 8];
    xfp[1] = &xbuf[1][lrow & 3][(lrow >> 2) * AST + quad * 8];
    const int habase = (lrow >> 2) * AST + quad * 8;  // h A-rows: replicated samples
    const __bf16* hfp[2] = { &hbuf[0][habase], &hbuf[1][habase] };
    __bf16* hwp[2] = { &hbuf[0][quad * AST + uu], &hbuf[1][quad * AST + uu] };

    __syncthreads();   // x(0..4), h(0) staged

    floatx4 xg[4];   // xg[gt][r] = bias + x(ts+r)@W_ih^T for (sample quad, unit uu)
#define XBLOCK(PP) do {                                                              \
        bf16x8 af_[4];                                                               \
        _Pragma("unroll") for (int kt = 0; kt < 4; ++kt)                             \
            af_[kt] = *(const bf16x8*)(xfp[PP] + kt * 32);                           \
        _Pragma("unroll") for (int gt = 0; gt < 4; ++gt) {                           \
            floatx4 a0 = {bini[gt], bini[gt], bini[gt], bini[gt]};                   \
            xg[gt] = a0;                                                             \
        }                                                                            \
        _Pragma("unroll") for (int kt = 0; kt < 4; ++kt)                             \
            _Pragma("unroll") for (int gt = 0; gt < 4; ++gt)                         \
                xg[gt] = __builtin_amdgcn_mfma_f32_16x16x32_bf16(af_[kt], wfx[gt][kt], xg[gt], 0, 0, 0); \
    } while (0)

    XBLOCK(0);   // xg for superstep 0 (t = 0..3)

    floatx4 acc[4] = {{0.f,0.f,0.f,0.f},{0.f,0.f,0.f,0.f},{0.f,0.f,0.f,0.f},{0.f,0.f,0.f,0.f}};

#define STEP(OFF) do {                                                               \
        const int t  = ts + OFF;                                                     \
        const int rp = OFF & 1;        /* h read parity (ts % 4 == 0) */             \
        bf16x8 ah_[4];                                                               \
        _Pragma("unroll") for (int kt = 0; kt < 4; ++kt)                             \
            ah_[kt] = *(const bf16x8*)(hfp[rp] + kt * 32);                           \
        _Pragma("unroll") for (int gt = 0; gt < 4; ++gt)                             \
            acc[gt][0] = xg[gt][OFF];  /* elems 1-3 don't-care (stale, finite) */    \
        _Pragma("unroll") for (int kt = 0; kt < 4; ++kt)                             \
            _Pragma("unroll") for (int gt = 0; gt < 4; ++gt)                         \
                acc[gt] = __builtin_amdgcn_mfma_f32_16x16x32_bf16(ah_[kt], wfh[gt][kt], acc[gt], 0, 0, 0); \
        const float ii = fsig(acc[0][0]);                                            \
        const float ff = fsig(acc[1][0]);                                            \
        const float g2 = ftanhf(acc[2][0]);                                          \
        const float oo = fsig(acc[3][0]);                                            \
        c = ff * c + ii * g2;                                                        \
        const float h = oo * ftanhf(c);                                              \
        if (t == tlast) hl = fmaxf(h, 0.0f);                                         \
        *hwp[1 - rp] = (__bf16)h;                                                    \
        { const int t5 = t + 5;                                                      \
          if (t5 < SEQ) {                                                            \
              xbuf[(t5 >> 2) & 1][t5 & 3][sm] = (__bf16)fmaxf(e, 0.0f);              \
              if (t5 + 1 < SEQ)                                                      \
                  e = emb[(size_t)tokens[bm * SEQ + t5 + 1] * DIM + u];              \
          } }                                                                        \
        if (OFF == 3 && ts + 4 < Lmax) { XBLOCK((((ts >> 2) + 1) & 1)); }            \
        __syncthreads();                                                             \
    } while (0)

    for (int ts = 0; ts < Lmax; ts += 4) {
        STEP(0); STEP(1); STEP(2); STEP(3);
    }
#undef STEP
#undef XBLOCK

    // ---- epilogue: out[b] = [relu(h_last) | onehot] @ linW^T + linb ----
    hlbuf[quad * HID + uu] = hl;
    __syncthreads();
    if (tid < 2 * BQ) {
        const int mm = tid >> 1, kk = tid & 1;
        const int bb = bid * BQ + mm;
        float a2 = linb[kk];
        for (int q = 0; q < HID; ++q)
            a2 += hlbuf[mm * HID + q] * linW[kk * FEAT + q];
        for (int o = 0; o < NOPS; ++o)
            a2 += onehot[bb * NOPS + o] * linW[kk * FEAT + HID + o];
        out[bb * 2 + kk] = a2;
    }
}

extern "C" void kernel_launch(void* const* d_in, const int* in_sizes, int n_in,
                              void* d_out, int out_size, void* d_ws, size_t ws_size,
                              hipStream_t stream) {
    const int*   tokens  = (const int*)d_in[0];
    const int*   lengths = (const int*)d_in[1];
    const float* onehot  = (const float*)d_in[2];
    const float* emb     = (const float*)d_in[3];
    const float* Wih     = (const float*)d_in[4];
    const float* Whh     = (const float*)d_in[5];
    const float* bih     = (const float*)d_in[6];
    const float* bhh     = (const float*)d_in[7];
    const float* h0      = (const float*)d_in[8];
    const float* c0      = (const float*)d_in[9];
    const float* linW    = (const float*)d_in[10];
    const float* linb    = (const float*)d_in[11];
    float* out = (float*)d_out;
    (void)in_sizes; (void)n_in; (void)out_size; (void)d_ws; (void)ws_size;

    lstm_fused<<<dim3(NB / BQ), dim3(512), 0, stream>>>(
        tokens, lengths, onehot, emb, Wih, Whh, bih, bhh, h0, c0, linW, linb, out);
}

// Round 5
// 593.884 us; speedup vs baseline: 1.0974x; 1.0974x over previous
//
#include <hip/hip_runtime.h>
#include <hip/hip_bf16.h>

// Problem constants
#define NB    1024   // batch
#define SEQ   512    // max seq len
#define DIM   128    // embedding dim (D)
#define HID   128    // hidden (H)
#define NOPS  16     // OPS
#define FEAT  144    // H + OPS
#define BQ    4      // samples per workgroup
#define AST   144    // LDS row stride (bf16 elems): breaks power-of-2 bank strides

typedef __bf16 bf16x8 __attribute__((ext_vector_type(8)));
typedef float  floatx4 __attribute__((ext_vector_type(4)));

__device__ __forceinline__ float fsig(float x)  { return 1.0f / (1.0f + __expf(-x)); }
__device__ __forceinline__ float ftanhf(float x){ return 2.0f / (1.0f + __expf(-2.0f * x)) - 1.0f; }

// LDS-only barrier (composable_kernel idiom): drains lgkmcnt but NOT vmcnt,
// so global embedding gathers stay in flight across the per-step barrier.
// __syncthreads() would emit s_waitcnt vmcnt(0) lgkmcnt(0) and serialize the
// ~200-900cyc gather latency onto every timestep (the R2-R4 hidden cost).
__device__ __forceinline__ void block_sync_lds() {
    asm volatile("s_waitcnt lgkmcnt(0)\n\ts_barrier" ::: "memory");
}

// One WG = 512 threads (8 waves) owns BQ=4 samples. Wave w owns unit-chunk w
// for all 4 gate types (gates consumed in-register, no gate LDS roundtrip).
// gates(t) = [bias + x(t)@W_ih^T] (precomputed at end of step t-1) +
// h(t)@W_hh^T (serial part). One LDS-only barrier per step; x/h double-
// buffered by parity; embedding gather prefetched 2 steps ahead (e0/e1).
__global__ __launch_bounds__(512, 2)
void lstm_fused(const int* __restrict__ tokens, const int* __restrict__ lengths,
                const float* __restrict__ onehot, const float* __restrict__ emb,
                const float* __restrict__ Wih, const float* __restrict__ Whh,
                const float* __restrict__ bih, const float* __restrict__ bhh,
                const float* __restrict__ h0, const float* __restrict__ c0,
                const float* __restrict__ linW, const float* __restrict__ linb,
                float* __restrict__ out)
{
    __shared__ __align__(16) __bf16 xbuf[2][BQ * AST];
    __shared__ __align__(16) __bf16 hbuf[2][BQ * AST];
    __shared__ __align__(16) float  hlbuf[BQ * HID];

    const int tid  = threadIdx.x;
    const int wave = tid >> 6;
    const int lane = tid & 63;
    const int quad = lane >> 4;
    const int lrow = lane & 15;
    const int bid  = blockIdx.x;

    // ---- Weight B-fragments in registers (loaded once). ----
    // B-layout (16x16x32): lane holds B[k=quad*8+j][n=lrow].
    bf16x8 wfx[4][4], wfh[4][4];
#pragma unroll
    for (int gt = 0; gt < 4; ++gt) {
        const int g = gt * 128 + wave * 16 + lrow;
#pragma unroll
        for (int kt = 0; kt < 4; ++kt) {
            const float* sx = Wih + g * DIM + kt * 32 + quad * 8;
            const float* sh = Whh + g * HID + kt * 32 + quad * 8;
            float4 a = *(const float4*)(sx);
            float4 b = *(const float4*)(sx + 4);
            bf16x8 v;
            v[0] = (__bf16)a.x; v[1] = (__bf16)a.y; v[2] = (__bf16)a.z; v[3] = (__bf16)a.w;
            v[4] = (__bf16)b.x; v[5] = (__bf16)b.y; v[6] = (__bf16)b.z; v[7] = (__bf16)b.w;
            wfx[gt][kt] = v;
            a = *(const float4*)(sh);
            b = *(const float4*)(sh + 4);
            v[0] = (__bf16)a.x; v[1] = (__bf16)a.y; v[2] = (__bf16)a.z; v[3] = (__bf16)a.w;
            v[4] = (__bf16)b.x; v[5] = (__bf16)b.y; v[6] = (__bf16)b.z; v[7] = (__bf16)b.w;
            wfh[gt][kt] = v;
        }
    }

    // ---- Per-lane state: sample = quad, unit = uu = wave*16 + lrow ----
    const int uu = wave * 16 + lrow;
    const int bq = bid * BQ + quad;
    int lenq = lengths[bq]; if (lenq < 1) lenq = 1;
    const int tlast = lenq - 1;

    int Lmax = 0;
#pragma unroll
    for (int s2 = 0; s2 < BQ; ++s2) {
        int l2 = lengths[bid * BQ + s2]; if (l2 < 1) l2 = 1;
        Lmax = (l2 > Lmax) ? l2 : Lmax;
    }

    float bini[4];
#pragma unroll
    for (int gt = 0; gt < 4; ++gt)
        bini[gt] = bih[gt * 128 + uu] + bhh[gt * 128 + uu];

    float c  = c0[uu];
    float hl = 0.0f;

    // ---- Staging thread layout: m = tid>>7 (sample), u = tid&127 (unit) ----
    const int m  = tid >> 7;
    const int u  = tid & 127;
    const int bm = bid * BQ + m;
    const int sm = m * AST + u;

    hbuf[0][sm] = (__bf16)h0[u];
    {
        float e0i = emb[(size_t)tokens[bm * SEQ] * DIM + u];
        xbuf[0][sm] = (__bf16)fmaxf(e0i, 0.0f);
        float e1i = emb[(size_t)tokens[bm * SEQ + 1] * DIM + u];
        xbuf[1][sm] = (__bf16)fmaxf(e1i, 0.0f);
    }
    // 2-deep gather pipeline: e0 -> x(t+2) consumed at step t (loaded at t-2)
    float e0 = emb[(size_t)tokens[bm * SEQ + 2] * DIM + u];
    float e1 = emb[(size_t)tokens[bm * SEQ + 3] * DIM + u];

    const int arow  = lrow >> 2;          // A row m -> sample m>>2
    const int abase = arow * AST + quad * 8;

    __syncthreads();   // x(0), x(1), h(0) staged

    // ---- Prologue: acc_x(0) = bias + x(0) @ W_ih^T ----
    floatx4 accx[4];
    {
        bf16x8 af[4];
#pragma unroll
        for (int kt = 0; kt < 4; ++kt)
            af[kt] = *(const bf16x8*)&xbuf[0][abase + kt * 32];
#pragma unroll
        for (int gt = 0; gt < 4; ++gt) {
            floatx4 a0 = {bini[gt], bini[gt], bini[gt], bini[gt]};
            accx[gt] = a0;
        }
#pragma unroll
        for (int kt = 0; kt < 4; ++kt)
#pragma unroll
            for (int gt = 0; gt < 4; ++gt)
                accx[gt] = __builtin_amdgcn_mfma_f32_16x16x32_bf16(af[kt], wfx[gt][kt], accx[gt], 0, 0, 0);
    }
    __syncthreads();   // pre-loop x(0) reads retired before iter-0 stages x(2)

    for (int t = 0; t < Lmax; ++t) {
        const int p = t & 1;

        // h(t) fragments
        bf16x8 ah[4];
#pragma unroll
        for (int kt = 0; kt < 4; ++kt)
            ah[kt] = *(const bf16x8*)&hbuf[p][abase + kt * 32];

        // gates(t) = acc_x(t) + h(t) @ W_hh^T   (the serial MFMAs)
        floatx4 acc[4];
#pragma unroll
        for (int gt = 0; gt < 4; ++gt) acc[gt] = accx[gt];
#pragma unroll
        for (int kt = 0; kt < 4; ++kt)
#pragma unroll
            for (int gt = 0; gt < 4; ++gt)
                acc[gt] = __builtin_amdgcn_mfma_f32_16x16x32_bf16(ah[kt], wfh[gt][kt], acc[gt], 0, 0, 0);

        // cell update; C/D rows quad*4+r all = sample quad -> take elem 0
        const float ii = fsig(acc[0][0]);
        const float ff = fsig(acc[1][0]);
        const float g2 = ftanhf(acc[2][0]);
        const float oo = fsig(acc[3][0]);
        c = ff * c + ii * g2;
        const float h = oo * ftanhf(c);
        if (t == tlast) hl = fmaxf(h, 0.0f);

        // h(t+1) -> other parity buffer
        hbuf[1 - p][quad * AST + uu] = (__bf16)h;

        // stage x(t+2) = relu(e0) (loaded at t-2); advance gather pipeline
        if (t + 2 < SEQ) {
            xbuf[p][sm] = (__bf16)fmaxf(e0, 0.0f);
            e0 = e1;
            if (t + 4 < SEQ)
                e1 = emb[(size_t)tokens[bm * SEQ + t + 4] * DIM + u];
        }

        // pre-compute acc_x(t+1) = bias + x(t+1) @ W_ih^T (fills MFMA pipe
        // while other waves finish activation / wait at barrier)
        if (t + 1 < Lmax) {
            bf16x8 af[4];
#pragma unroll
            for (int kt = 0; kt < 4; ++kt)
                af[kt] = *(const bf16x8*)&xbuf[1 - p][abase + kt * 32];
#pragma unroll
            for (int gt = 0; gt < 4; ++gt) {
                floatx4 a0 = {bini[gt], bini[gt], bini[gt], bini[gt]};
                accx[gt] = a0;
            }
#pragma unroll
            for (int kt = 0; kt < 4; ++kt)
#pragma unroll
                for (int gt = 0; gt < 4; ++gt)
                    accx[gt] = __builtin_amdgcn_mfma_f32_16x16x32_bf16(af[kt], wfx[gt][kt], accx[gt], 0, 0, 0);
        }

        // single LDS-only barrier per step (global gathers stay in flight)
        block_sync_lds();
    }

    // ---- epilogue: out[b] = [relu(h_last) | onehot] @ linW^T + linb ----
    hlbuf[quad * HID + uu] = hl;
    __syncthreads();
    if (tid < 2 * BQ) {
        const int mm = tid >> 1, kk = tid & 1;
        const int bb = bid * BQ + mm;
        float a2 = linb[kk];
        for (int q = 0; q < HID; ++q)
            a2 += hlbuf[mm * HID + q] * linW[kk * FEAT + q];
        for (int o = 0; o < NOPS; ++o)
            a2 += onehot[bb * NOPS + o] * linW[kk * FEAT + HID + o];
        out[bb * 2 + kk] = a2;
    }
}

extern "C" void kernel_launch(void* const* d_in, const int* in_sizes, int n_in,
                              void* d_out, int out_size, void* d_ws, size_t ws_size,
                              hipStream_t stream) {
    const int*   tokens  = (const int*)d_in[0];
    const int*   lengths = (const int*)d_in[1];
    const float* onehot  = (const float*)d_in[2];
    const float* emb     = (const float*)d_in[3];
    const float* Wih     = (const float*)d_in[4];
    const float* Whh     = (const float*)d_in[5];
    const float* bih     = (const float*)d_in[6];
    const float* bhh     = (const float*)d_in[7];
    const float* h0      = (const float*)d_in[8];
    const float* c0      = (const float*)d_in[9];
    const float* linW    = (const float*)d_in[10];
    const float* linb    = (const float*)d_in[11];
    float* out = (float*)d_out;
    (void)in_sizes; (void)n_in; (void)out_size; (void)d_ws; (void)ws_size;

    lstm_fused<<<dim3(NB / BQ), dim3(512), 0, stream>>>(
        tokens, lengths, onehot, emb, Wih, Whh, bih, bhh, h0, c0, linW, linb, out);
}

// Round 6
// 569.606 us; speedup vs baseline: 1.1442x; 1.0426x over previous
//
#include <hip/hip_runtime.h>
#include <hip/hip_bf16.h>

// Problem constants
#define NB    1024   // batch
#define SEQ   512    // max seq len
#define DIM   128    // embedding dim (D)
#define HID   128    // hidden (H)
#define NOPS  16     // OPS
#define FEAT  144    // H + OPS
#define BQ    4      // samples per workgroup
#define AST   144    // sample stride inside a slot (bf16): breaks pow-2 bank strides
#define XST   578    // x slot stride (bf16) = 289 dwords, odd mod 32 -> ~2-way frag reads

typedef __bf16 bf16x8 __attribute__((ext_vector_type(8)));
typedef float  floatx4 __attribute__((ext_vector_type(4)));

__device__ __forceinline__ float fsig(float x)  { return 1.0f / (1.0f + __expf(-x)); }
__device__ __forceinline__ float ftanhf(float x){ return 2.0f / (1.0f + __expf(-2.0f * x)) - 1.0f; }

// LDS-only barrier: drains lgkmcnt (all cross-wave traffic is LDS), leaves
// global gathers in flight.
__device__ __forceinline__ void block_sync_lds() {
    asm volatile("s_waitcnt lgkmcnt(0)\n\ts_barrier" ::: "memory");
}

// One WG = 512 threads (8 waves) owns BQ=4 samples. Wave w owns unit-chunk w
// for all 4 gate types (gates consumed in-register). 4-STEP X-PACKING: one
// MFMA block per superstep computes x-gates for 4 samples x 4 timesteps
// (A row = sample*4 + off); C/D row quad*4+r -> x-gate(sample=quad, ts+r, uu)
// lands in lane (quad,lrow) reg r. In-loop serial MFMAs are h-part only
// (16/wave/step, fed C=xg directly -> no acc copies, no bias splats, no gate
// extraction selects). 8 rotating x-slots (stride 578 = odd dwords: ~2-way
// bank access on packed frag reads -- the R4 bug was stride==0 mod 128B).
// One LDS barrier per step; h double-buffered by step parity (compile-time
// via 4x unroll); x staged 5 steps ahead, embedding row prefetched 1 deeper.
__global__ __launch_bounds__(512, 2)
void lstm_fused(const int* __restrict__ tokens, const int* __restrict__ lengths,
                const float* __restrict__ onehot, const float* __restrict__ emb,
                const float* __restrict__ Wih, const float* __restrict__ Whh,
                const float* __restrict__ bih, const float* __restrict__ bhh,
                const float* __restrict__ h0, const float* __restrict__ c0,
                const float* __restrict__ linW, const float* __restrict__ linb,
                float* __restrict__ out)
{
    __shared__ __align__(16) __bf16 xbuf[8 * XST];        // 8 rotating x slots
    __shared__ __align__(16) __bf16 hbuf[2 * BQ * AST];   // h, parity by t&1
    __shared__ __align__(16) float  hlbuf[BQ * HID];

    const int tid  = threadIdx.x;
    const int wave = tid >> 6;
    const int lane = tid & 63;
    const int quad = lane >> 4;
    const int lrow = lane & 15;
    const int bid  = blockIdx.x;

    // ---- Weight B-fragments in registers (loaded once). ----
    // B-layout (16x16x32): lane holds B[k=quad*8+j][n=lrow].
    bf16x8 wfx[4][4], wfh[4][4];
#pragma unroll
    for (int gt = 0; gt < 4; ++gt) {
        const int g = gt * 128 + wave * 16 + lrow;
#pragma unroll
        for (int kt = 0; kt < 4; ++kt) {
            const float* sx = Wih + g * DIM + kt * 32 + quad * 8;
            const float* sh = Whh + g * HID + kt * 32 + quad * 8;
            float4 a = *(const float4*)(sx);
            float4 b = *(const float4*)(sx + 4);
            bf16x8 v;
            v[0] = (__bf16)a.x; v[1] = (__bf16)a.y; v[2] = (__bf16)a.z; v[3] = (__bf16)a.w;
            v[4] = (__bf16)b.x; v[5] = (__bf16)b.y; v[6] = (__bf16)b.z; v[7] = (__bf16)b.w;
            wfx[gt][kt] = v;
            a = *(const float4*)(sh);
            b = *(const float4*)(sh + 4);
            v[0] = (__bf16)a.x; v[1] = (__bf16)a.y; v[2] = (__bf16)a.z; v[3] = (__bf16)a.w;
            v[4] = (__bf16)b.x; v[5] = (__bf16)b.y; v[6] = (__bf16)b.z; v[7] = (__bf16)b.w;
            wfh[gt][kt] = v;
        }
    }

    // ---- Per-lane state: sample = quad, unit = uu = wave*16 + lrow ----
    const int uu = wave * 16 + lrow;
    const int bq = bid * BQ + quad;
    int lenq = lengths[bq]; if (lenq < 1) lenq = 1;
    const int tlast = lenq - 1;

    int Lmax = 0;
#pragma unroll
    for (int s2 = 0; s2 < BQ; ++s2) {
        int l2 = lengths[bid * BQ + s2]; if (l2 < 1) l2 = 1;
        Lmax = (l2 > Lmax) ? l2 : Lmax;
    }

    // persistent bias C-registers: accx chains start from these (no splats)
    floatx4 biasC[4];
#pragma unroll
    for (int gt = 0; gt < 4; ++gt) {
        const float bgt = bih[gt * 128 + uu] + bhh[gt * 128 + uu];
        floatx4 a0 = {bgt, bgt, bgt, bgt};
        biasC[gt] = a0;
    }

    float c  = c0[uu];
    float hl = 0.0f;

    // ---- Staging thread layout: m = tid>>7 (sample), u = tid&127 (unit) ----
    const int m  = tid >> 7;
    const int u  = tid & 127;
    const int bm = bid * BQ + m;
    const int sm = m * AST + u;

    hbuf[sm] = (__bf16)h0[u];
#pragma unroll
    for (int k = 0; k <= 4; ++k) {   // stage x(0..4) into slots 0..4
        float ek = emb[(size_t)tokens[bm * SEQ + k] * DIM + u];
        xbuf[k * XST + sm] = (__bf16)fmaxf(ek, 0.0f);
    }
    float e = emb[(size_t)tokens[bm * SEQ + 5] * DIM + u];   // row for x(5)

    // frag pointers
    const int xfbase = (lrow & 3) * XST + (lrow >> 2) * AST + quad * 8;
    const __bf16* const xfp[2] = { &xbuf[xfbase], &xbuf[4 * XST + xfbase] };
    const int habase = (lrow >> 2) * AST + quad * 8;
    const __bf16* const hf[2] = { &hbuf[habase], &hbuf[BQ * AST + habase] };
    __bf16* const hw[2] = { &hbuf[quad * AST + uu], &hbuf[BQ * AST + quad * AST + uu] };
    __bf16* const xw = &xbuf[sm];

    __syncthreads();   // x(0..4), h(0) staged

    // xg[gt][r] = bias + x(ts+r)@W_ih^T for (sample quad, unit uu)
    floatx4 xg[4];
#define XBLOCK(G) do {                                                               \
        bf16x8 af_[4];                                                               \
        _Pragma("unroll") for (int kt = 0; kt < 4; ++kt)                             \
            af_[kt] = *(const bf16x8*)(xfp[G] + kt * 32);                            \
        _Pragma("unroll") for (int gt = 0; gt < 4; ++gt)                             \
            xg[gt] = __builtin_amdgcn_mfma_f32_16x16x32_bf16(af_[0], wfx[gt][0], biasC[gt], 0, 0, 0); \
        _Pragma("unroll") for (int kt = 1; kt < 4; ++kt)                             \
            _Pragma("unroll") for (int gt = 0; gt < 4; ++gt)                         \
                xg[gt] = __builtin_amdgcn_mfma_f32_16x16x32_bf16(af_[kt], wfx[gt][kt], xg[gt], 0, 0, 0); \
    } while (0)

    XBLOCK(0);   // xg for superstep 0 (t = 0..3); reads slots 0-3, no hazard
                 // with iter-0 staging (targets slot 5)

    // OFF is a literal 0..3: parity/slot/extract-index all compile-time.
    // h-MFMA chain takes C = xg[gt] directly (D != C, xg preserved); row
    // quad*4+r holds xg(t_s+r) + hpart(sample quad) -> elem OFF is gates(t).
#define STEP(OFF) do {                                                               \
        const int t  = ts + OFF;                                                     \
        bf16x8 ah_[4];                                                               \
        _Pragma("unroll") for (int kt = 0; kt < 4; ++kt)                             \
            ah_[kt] = *(const bf16x8*)(hf[OFF & 1] + kt * 32);                       \
        floatx4 acc[4];                                                              \
        _Pragma("unroll") for (int gt = 0; gt < 4; ++gt)                             \
            acc[gt] = __builtin_amdgcn_mfma_f32_16x16x32_bf16(ah_[0], wfh[gt][0], xg[gt], 0, 0, 0); \
        _Pragma("unroll") for (int kt = 1; kt < 4; ++kt)                             \
            _Pragma("unroll") for (int gt = 0; gt < 4; ++gt)                         \
                acc[gt] = __builtin_amdgcn_mfma_f32_16x16x32_bf16(ah_[kt], wfh[gt][kt], acc[gt], 0, 0, 0); \
        const float ii = fsig(acc[0][OFF]);                                          \
        const float ff = fsig(acc[1][OFF]);                                          \
        const float g2 = ftanhf(acc[2][OFF]);                                        \
        const float oo = fsig(acc[3][OFF]);                                          \
        c = ff * c + ii * g2;                                                        \
        const float h = oo * ftanhf(c);                                              \
        if (t == tlast) hl = fmaxf(h, 0.0f);                                         \
        *hw[1 - (OFF & 1)] = (__bf16)h;                                              \
        if (t + 5 < SEQ) {   /* stage x(t+5); slot rotation, compile-time OFF */     \
            const int slot = (OFF == 3) ? (4 * g) : (4 * (1 - g) + OFF + 1);         \
            xw[slot * XST] = (__bf16)fmaxf(e, 0.0f);                                 \
            if (t + 6 < SEQ)                                                         \
                e = emb[(size_t)tokens[bm * SEQ + t + 6] * DIM + u];                 \
        }                                                                            \
        if (OFF == 3 && ts + 4 < Lmax) { XBLOCK(1 - g); }                            \
        block_sync_lds();                                                            \
    } while (0)

    for (int ts = 0; ts < Lmax; ts += 4) {
        const int g = (ts >> 2) & 1;
        STEP(0); STEP(1); STEP(2); STEP(3);
    }
#undef STEP
#undef XBLOCK

    // ---- epilogue: out[b] = [relu(h_last) | onehot] @ linW^T + linb ----
    hlbuf[quad * HID + uu] = hl;
    __syncthreads();
    if (tid < 2 * BQ) {
        const int mm = tid >> 1, kk = tid & 1;
        const int bb = bid * BQ + mm;
        float a2 = linb[kk];
        for (int q = 0; q < HID; ++q)
            a2 += hlbuf[mm * HID + q] * linW[kk * FEAT + q];
        for (int o = 0; o < NOPS; ++o)
            a2 += onehot[bb * NOPS + o] * linW[kk * FEAT + HID + o];
        out[bb * 2 + kk] = a2;
    }
}

extern "C" void kernel_launch(void* const* d_in, const int* in_sizes, int n_in,
                              void* d_out, int out_size, void* d_ws, size_t ws_size,
                              hipStream_t stream) {
    const int*   tokens  = (const int*)d_in[0];
    const int*   lengths = (const int*)d_in[1];
    const float* onehot  = (const float*)d_in[2];
    const float* emb     = (const float*)d_in[3];
    const float* Wih     = (const float*)d_in[4];
    const float* Whh     = (const float*)d_in[5];
    const float* bih     = (const float*)d_in[6];
    const float* bhh     = (const float*)d_in[7];
    const float* h0      = (const float*)d_in[8];
    const float* c0      = (const float*)d_in[9];
    const float* linW    = (const float*)d_in[10];
    const float* linb    = (const float*)d_in[11];
    float* out = (float*)d_out;
    (void)in_sizes; (void)n_in; (void)out_size; (void)d_ws; (void)ws_size;

    lstm_fused<<<dim3(NB / BQ), dim3(512), 0, stream>>>(
        tokens, lengths, onehot, emb, Wih, Whh, bih, bhh, h0, c0, linW, linb, out);
}